// Round 14
// baseline (72.603 us; speedup 1.0000x reference)
//
#include <hip/hip_runtime.h>

// TopKGate via split-precision f16 MFMA (no fp32 MFMA on CDNA4):
//   x = xh + xl/4096, w = wh + wl/4096 (f16 planes, lo pre-scaled x4096)
//   logits = xh*wh + (xh*wl' + xl'*wh)/4096
// R14: ZERO barriers in the main loop. Each of the 4 waves (kh x nh) stages
// its own x[16][32] + w[32exp][32k] slices into PRIVATE LDS (6 global_load_lds
// per chunk), double-buffered, synced only by its own counted vmcnt(6).
// 1024 blocks (4/CU, 16 waves/CU), mfma_f32_16x16x32_f16, LDS 32 KB.

typedef __attribute__((ext_vector_type(8))) _Float16 half8;
typedef __attribute__((ext_vector_type(4))) float f32x4;

constexpr int DD   = 2048;
constexpr int EE   = 64;
constexpr int BM   = 16;         // tokens per block
constexpr int BK   = 64;         // k per chunk (each wave: one 32-k half)
constexpr int NCH  = DD / BK;    // 32 chunks

#define WVM(N)  asm volatile("s_waitcnt vmcnt(" #N ")" ::: "memory")

// ---- pre-kernel: Wg [2048][64] -> planes [kc][kh][n][32 halves] ----
// 8-half block bq (0..3) of expert n stored at position bq ^ (n&3).
__global__ __launch_bounds__(256) void wsplit_kernel(
    const float* __restrict__ Wg, _Float16* __restrict__ whT2,
    _Float16* __restrict__ wlT2)
{
    __shared__ float xl[32][65];
    const int tid = threadIdx.x;
    const int kc  = blockIdx.x >> 1;     // 64 blocks
    const int kh  = blockIdx.x & 1;
    const int k0  = kc * 64 + kh * 32;

#pragma unroll
    for (int r = 0; r < 2; ++r) {
        int slot = tid + r * 256;        // float4 slots 0..511
        int row = slot >> 4, c4 = (slot & 15) << 2;
        *(float4*)&xl[row][c4] = *(const float4*)&Wg[(size_t)(k0 + row) * EE + c4];
    }
    __syncthreads();

    const int n  = tid >> 2;             // expert 0..63
    const int bq = tid & 3;              // 8-k block within the 32
    _Float16 hh[8], ll[8];
#pragma unroll
    for (int j = 0; j < 8; ++j) {
        float v = xl[bq * 8 + j][n];
        _Float16 h = (_Float16)v;
        hh[j] = h;
        ll[j] = (_Float16)((v - (float)h) * 4096.f);
    }
    const size_t base = ((size_t)(kc * 2 + kh) * 64 + n) * 32 + (bq ^ (n & 3)) * 8;
    *(half8*)&whT2[base] = *(const half8*)&hh[0];
    *(half8*)&wlT2[base] = *(const half8*)&ll[0];
}

__global__ __launch_bounds__(256, 4) void gate_kernel(
    const float* __restrict__ x, const _Float16* __restrict__ whT2,
    const _Float16* __restrict__ wlT2,
    float* __restrict__ gate_out, float* __restrict__ idx_out,
    float* __restrict__ pSum, float* __restrict__ pCnt)
{
    __shared__ __align__(16) union {
        struct {
            float    xs[4][2][16][32];       // per-wave x slice, 16 KB
            _Float16 wsb[4][2][2][32][32];   // per-wave w slabs,  16 KB
        } st;
        struct { float logits[2][BM][68]; float auxsm[2][4][64]; } ep;
    } sm;

    const int tid  = threadIdx.x;
    const int wv   = tid >> 6;
    const int lane = tid & 63;
    const int kh   = wv & 1;             // k-half of chunk (32 k's)
    const int nh   = wv >> 1;            // expert-half (32 experts)
    const size_t tok0 = (size_t)blockIdx.x * BM;

    // per-wave private stage of chunk c: 2 x-loads + 4 w-loads per lane
    auto stage = [&](int buf, int c) {
        const float* xg = x + tok0 * DD + c * BK + kh * 32;
#pragma unroll
        for (int r = 0; r < 2; ++r) {
            int s   = lane + r * 64;             // float4 slot 0..127
            int row = s >> 3, q = s & 7;
            int qs  = q ^ ((row & 3) << 1);      // source-swizzled float4
            __builtin_amdgcn_global_load_lds(
                xg + (size_t)row * DD + qs * 4,
                &sm.st.xs[wv][buf][row][q * 4], 16, 0, 0);
        }
        const size_t wbase = ((size_t)(c * 2 + kh) * 64 + nh * 32) * 32;
#pragma unroll
        for (int p = 0; p < 2; ++p) {
            const _Float16* wg = (p ? wlT2 : whT2) + wbase;
            _Float16* dst = &sm.st.wsb[wv][buf][p][0][0];
#pragma unroll
            for (int r = 0; r < 2; ++r) {
                int s = lane + r * 64;           // 8-half slot 0..127
                __builtin_amdgcn_global_load_lds(wg + s * 8, dst + s * 8, 16, 0, 0);
            }
        }
    };

    f32x4 accH0 = {0.f,0.f,0.f,0.f}, accL0 = {0.f,0.f,0.f,0.f};
    f32x4 accH1 = {0.f,0.f,0.f,0.f}, accL1 = {0.f,0.f,0.f,0.f};

    const int arow = lane & 15;                  // token row / B col
    const int kg   = lane >> 4;                  // k-group 0..3
    const int fidx = (kg ^ (arow & 3)) * 8;      // swizzled x float offset
    const int wsl  = (kg ^ (arow & 3)) * 8;      // swizzled w half offset (e&3==arow&3)
    const int e0l  = arow;                       // expert-local, tile 0
    const int e1l  = arow + 16;                  // tile 1 (same &3 -> same slot)

    auto compute = [&](int buf) {
        float4 xa = *(const float4*)&sm.st.xs[wv][buf][arow][fidx];
        float4 xb = *(const float4*)&sm.st.xs[wv][buf][arow][fidx + 4];
        half8 ah, al;
#define CVT(E, V)                                                              \
        { _Float16 h = (_Float16)(V); ah[E] = h;                               \
          al[E] = (_Float16)(((V) - (float)h) * 4096.f); }
        CVT(0, xa.x) CVT(1, xa.y) CVT(2, xa.z) CVT(3, xa.w)
        CVT(4, xb.x) CVT(5, xb.y) CVT(6, xb.z) CVT(7, xb.w)
#undef CVT
        half8 bh0 = *(const half8*)&sm.st.wsb[wv][buf][0][e0l][wsl];
        half8 bl0 = *(const half8*)&sm.st.wsb[wv][buf][1][e0l][wsl];
        half8 bh1 = *(const half8*)&sm.st.wsb[wv][buf][0][e1l][wsl];
        half8 bl1 = *(const half8*)&sm.st.wsb[wv][buf][1][e1l][wsl];
        accH0 = __builtin_amdgcn_mfma_f32_16x16x32_f16(ah, bh0, accH0, 0, 0, 0);
        accL0 = __builtin_amdgcn_mfma_f32_16x16x32_f16(ah, bl0, accL0, 0, 0, 0);
        accL0 = __builtin_amdgcn_mfma_f32_16x16x32_f16(al, bh0, accL0, 0, 0, 0);
        accH1 = __builtin_amdgcn_mfma_f32_16x16x32_f16(ah, bh1, accH1, 0, 0, 0);
        accL1 = __builtin_amdgcn_mfma_f32_16x16x32_f16(ah, bl1, accL1, 0, 0, 0);
        accL1 = __builtin_amdgcn_mfma_f32_16x16x32_f16(al, bh1, accL1, 0, 0, 0);
    };

    // per-wave 2-deep pipeline, no barriers: WVM(6) waits own chunk-c stage
    stage(0, 0);
    stage(1, 1);
#pragma unroll 1
    for (int c = 0; c < NCH - 1; ++c) {
        const int buf = c & 1;
        WVM(6);                               // stage(c) landed; (c+1) in flight
        compute(buf);
        if (c + 2 < NCH) stage(buf, c + 2);
    }
    WVM(0);                                   // last stage drained
    compute((NCH - 1) & 1);

    // ---- C -> logits LDS (m89-verified layout), combine planes ----
    __syncthreads();                          // before union reuse
    const float inv = 1.f / 4096.f;
#pragma unroll
    for (int e = 0; e < 4; ++e) {
        const int row = (lane >> 4) * 4 + e;  // token 0..15
        sm.ep.logits[kh][row][nh * 32 + e0l] = accH0[e] + accL0[e] * inv;
        sm.ep.logits[kh][row][nh * 32 + e1l] = accH1[e] + accL1[e] * inv;
    }
    __syncthreads();

    // ---- epilogue: wave wv -> tokens [wv*4, wv*4+4); lane = expert ----
    float sumP_acc = 0.f;
    float cnt_acc  = 0.f;
#pragma unroll 1
    for (int tt = 0; tt < 4; ++tt) {
        const int tl = wv * 4 + tt;
        const size_t t = tok0 + tl;
        float v = sm.ep.logits[0][tl][lane] + sm.ep.logits[1][tl][lane];

        float m = v;
#pragma unroll
        for (int off = 32; off; off >>= 1) m = fmaxf(m, __shfl_xor(m, off, 64));
        float p = expf(v - m);
        float s = p;
#pragma unroll
        for (int off = 32; off; off >>= 1) s += __shfl_xor(s, off, 64);
        float prob = p / s;
        sumP_acc += prob;

        // top-1 (ties -> lowest index, matches lax.top_k)
        float bv = prob; int bi = lane;
#pragma unroll
        for (int off = 32; off; off >>= 1) {
            float ov = __shfl_xor(bv, off, 64);
            int   oi = __shfl_xor(bi, off, 64);
            if (ov > bv || (ov == bv && oi < bi)) { bv = ov; bi = oi; }
        }
        // top-2
        float v2 = (lane == bi) ? -1.f : prob;
        float bv2 = v2; int bi2 = lane;
#pragma unroll
        for (int off = 32; off; off >>= 1) {
            float ov = __shfl_xor(bv2, off, 64);
            int   oi = __shfl_xor(bi2, off, 64);
            if (ov > bv2 || (ov == bv2 && oi < bi2)) { bv2 = ov; bi2 = oi; }
        }

        float denom = bv + bv2;
        float g1 = bv / denom, g2 = bv2 / denom;
        float g = (lane == bi) ? g1 : ((lane == bi2) ? g2 : 0.f);
        gate_out[t * EE + lane] = g;
        if (lane == 0) {
            idx_out[2 * t]     = (float)bi;
            idx_out[2 * t + 1] = (float)bi2;
        }
        cnt_acc += (lane == bi)  ? 1.f : 0.f;
        cnt_acc += (lane == bi2) ? 1.f : 0.f;
    }

    // ---- per-block aux partials (deterministic) ----
    sm.ep.auxsm[0][wv][lane] = sumP_acc;
    sm.ep.auxsm[1][wv][lane] = cnt_acc;
    __syncthreads();
    if (wv == 0) {
        float sp = 0.f, c2 = 0.f;
#pragma unroll
        for (int w = 0; w < 4; ++w) {
            sp += sm.ep.auxsm[0][w][lane];
            c2 += sm.ep.auxsm[1][w][lane];
        }
        pSum[(size_t)blockIdx.x * 64 + lane] = sp;
        pCnt[(size_t)blockIdx.x * 64 + lane] = c2;
    }
}

// parallel aux reduction: 1024 threads (16 waves), 4-deep ILP + LDS reduce
__global__ __launch_bounds__(1024) void aux_kernel(
    const float* __restrict__ pSum, const float* __restrict__ pCnt,
    float* __restrict__ aux_out, int nblocks, float scale)
{
    const int tid  = threadIdx.x;
    const int wv   = tid >> 6;       // 0..15
    const int lane = tid & 63;       // = expert id
    __shared__ float smem[2][16][64];

    float sp[4] = {0.f, 0.f, 0.f, 0.f};
    float cc[4] = {0.f, 0.f, 0.f, 0.f};
    for (int b = wv * 4; b < nblocks; b += 64) {
#pragma unroll
        for (int u = 0; u < 4; ++u) {
            sp[u] += pSum[(size_t)(b + u) * 64 + lane];
            cc[u] += pCnt[(size_t)(b + u) * 64 + lane];
        }
    }
    smem[0][wv][lane] = (sp[0] + sp[1]) + (sp[2] + sp[3]);
    smem[1][wv][lane] = (cc[0] + cc[1]) + (cc[2] + cc[3]);
    __syncthreads();
    if (wv == 0) {
        float SP = 0.f, C = 0.f;
#pragma unroll
        for (int w = 0; w < 16; ++w) {
            SP += smem[0][w][lane];
            C  += smem[1][w][lane];
        }
        float prod = SP * C;
#pragma unroll
        for (int off = 32; off; off >>= 1) prod += __shfl_xor(prod, off, 64);
        if (lane == 0) aux_out[0] = prod * scale;
    }
}

extern "C" void kernel_launch(void* const* d_in, const int* in_sizes, int n_in,
                              void* d_out, int out_size, void* d_ws, size_t ws_size,
                              hipStream_t stream) {
    const float* x  = (const float*)d_in[0];
    const float* Wg = (const float*)d_in[1];
    const int T = in_sizes[0] / DD;          // 16384

    float* out      = (float*)d_out;
    float* gate_out = out;                                // T*64
    float* idx_out  = out + (size_t)T * EE;               // T*2 (as float)
    float* aux_out  = idx_out + (size_t)T * 2;            // 1

    const int nblocks = T / BM;                           // 1024
    _Float16* whT2 = (_Float16*)d_ws;                     // 256 KB
    _Float16* wlT2 = whT2 + (size_t)EE * DD;              // 256 KB
    float* pSum = (float*)(wlT2 + (size_t)EE * DD);       // 256 KB
    float* pCnt = pSum + (size_t)nblocks * 64;            // 256 KB

    wsplit_kernel<<<64, 256, 0, stream>>>(Wg, whT2, wlT2);
    gate_kernel<<<nblocks, 256, 0, stream>>>(x, whT2, wlT2,
                                             gate_out, idx_out, pSum, pCnt);

    const float scale = (float)EE / ((float)T * (float)T);
    aux_kernel<<<1, 1024, 0, stream>>>(pSum, pCnt, aux_out, nblocks, scale);
}

// Round 15
// 69.593 us; speedup vs baseline: 1.0433x; 1.0433x over previous
//
#include <hip/hip_runtime.h>

// TopKGate via split-precision f16 MFMA (no fp32 MFMA on CDNA4):
//   x = xh + xl/4096, w = wh + wl/4096 (f16 planes, lo pre-scaled x4096)
//   logits = xh*wh + (xh*wl' + xl'*wh)/4096
// R15: ZERO LDS / ZERO barriers in the main loop. Both operands load directly
// into MFMA fragments: x per-lane from global (16 rows x 128B per wave), w from
// a fragment-linear pre-permuted buffer (one coalesced dwordx4 per B-frag).
// 2-deep software pipeline with uniform s_waitcnt vmcnt(6) fences.
// Block: 4 waves = (kh: K-half) x (nh: expert-half); BM=16; grid 1024.

typedef __attribute__((ext_vector_type(8))) _Float16 half8;
typedef __attribute__((ext_vector_type(4))) float f32x4;

constexpr int DD = 2048;
constexpr int EE = 64;
constexpr int BM = 16;           // tokens per block

#define WVM(N) asm volatile("s_waitcnt vmcnt(" #N ")" ::: "memory")

// ---- pre-kernel: Wg[2048][64] -> fragment-linear wF ----
// wF[(((kc*4 + t)*2 + p)*64 + l)*8 + j] = plane_p( Wg[kc*32 + (l>>4)*8 + j][t*16 + (l&15)] )
__global__ __launch_bounds__(256) void wsplit_kernel(
    const float* __restrict__ Wg, _Float16* __restrict__ wF)
{
    __shared__ float xl[32][65];
    const int tid = threadIdx.x;
    const int kc  = blockIdx.x;          // 64 blocks, 32 k's each
    const int k0  = kc * 32;
#pragma unroll
    for (int r = 0; r < 2; ++r) {
        int slot = tid + r * 256;        // float4 slots 0..511
        int row = slot >> 4, c4 = (slot & 15) << 2;
        *(float4*)&xl[row][c4] = *(const float4*)&Wg[(size_t)(k0 + row) * EE + c4];
    }
    __syncthreads();
    const int t = tid >> 6, l = tid & 63;
    const int e  = t * 16 + (l & 15);
    const int kl = (l >> 4) * 8;
    half8 hh, ll;
#pragma unroll
    for (int j = 0; j < 8; ++j) {
        float v = xl[kl + j][e];
        _Float16 h = (_Float16)v;
        hh[j] = h;
        ll[j] = (_Float16)((v - (float)h) * 4096.f);
    }
    const size_t base = ((size_t)(kc * 4 + t) * 2) * 512 + (size_t)l * 8;
    *(half8*)&wF[base]       = hh;       // plane 0 (hi)
    *(half8*)&wF[base + 512] = ll;       // plane 1 (lo)
}

__global__ __launch_bounds__(256, 4) void gate_kernel(
    const float* __restrict__ x, const _Float16* __restrict__ wF,
    float* __restrict__ gate_out, float* __restrict__ idx_out,
    float* __restrict__ pSum, float* __restrict__ pCnt)
{
    __shared__ float red[2][BM][68];     // kh-partials of logits (~8.7 KB)
    __shared__ float auxsm[2][4][64];

    const int tid  = threadIdx.x;
    const int wv   = tid >> 6;
    const int lane = tid & 63;
    const int kh   = wv & 1;             // K-half (1024 k's, 32 chunks of 32)
    const int nh   = wv >> 1;            // expert-half (tiles 2nh, 2nh+1)
    const size_t tok0 = (size_t)blockIdx.x * BM;

    // x: lane's A-fragment address (row = token, cols (lane>>4)*8 ..)
    const float* xp = x + (tok0 + (lane & 15)) * DD + kh * 1024 + (lane >> 4) * 8;
    // w: fragment-linear pointers for (tile, plane); chunk stride 4096 halves
    const _Float16* w0 = wF + (((size_t)(kh * 32) * 4 + nh * 2    ) * 2    ) * 512 + (size_t)lane * 8;
    const _Float16* w1 = w0 + 512;
    const _Float16* w2 = wF + (((size_t)(kh * 32) * 4 + nh * 2 + 1) * 2    ) * 512 + (size_t)lane * 8;
    const _Float16* w3 = w2 + 512;

    f32x4 aH0 = {0.f,0.f,0.f,0.f}, aL0 = {0.f,0.f,0.f,0.f};
    f32x4 aH1 = {0.f,0.f,0.f,0.f}, aL1 = {0.f,0.f,0.f,0.f};

    float4 xa0, xb0, xa1, xb1;
    half8 h00, l00, h10, l10;            // even-chunk w frags (t0 hi/lo, t1 hi/lo)
    half8 h01, l01, h11, l11;            // odd-chunk w frags

#define LOADX(A, B, c)                                                         \
    do { A = *(const float4*)(xp + (size_t)(c) * 32);                          \
         B = *(const float4*)(xp + (size_t)(c) * 32 + 4); } while (0)
#define LOADW(H0, L0, H1, L1, c)                                               \
    do { const size_t o = (size_t)(c) * 4096;                                  \
         H0 = *(const half8*)(w0 + o); L0 = *(const half8*)(w1 + o);           \
         H1 = *(const half8*)(w2 + o); L1 = *(const half8*)(w3 + o); } while (0)
#define COMPUTE(XA, XB, H0, L0, H1, L1)                                        \
    do {                                                                       \
        half8 ah, al;                                                          \
        { float v;                                                             \
          v = XA.x; { _Float16 h=(_Float16)v; ah[0]=h; al[0]=(_Float16)((v-(float)h)*4096.f); } \
          v = XA.y; { _Float16 h=(_Float16)v; ah[1]=h; al[1]=(_Float16)((v-(float)h)*4096.f); } \
          v = XA.z; { _Float16 h=(_Float16)v; ah[2]=h; al[2]=(_Float16)((v-(float)h)*4096.f); } \
          v = XA.w; { _Float16 h=(_Float16)v; ah[3]=h; al[3]=(_Float16)((v-(float)h)*4096.f); } \
          v = XB.x; { _Float16 h=(_Float16)v; ah[4]=h; al[4]=(_Float16)((v-(float)h)*4096.f); } \
          v = XB.y; { _Float16 h=(_Float16)v; ah[5]=h; al[5]=(_Float16)((v-(float)h)*4096.f); } \
          v = XB.z; { _Float16 h=(_Float16)v; ah[6]=h; al[6]=(_Float16)((v-(float)h)*4096.f); } \
          v = XB.w; { _Float16 h=(_Float16)v; ah[7]=h; al[7]=(_Float16)((v-(float)h)*4096.f); } } \
        aH0 = __builtin_amdgcn_mfma_f32_16x16x32_f16(ah, H0, aH0, 0, 0, 0);    \
        aL0 = __builtin_amdgcn_mfma_f32_16x16x32_f16(ah, L0, aL0, 0, 0, 0);    \
        aL0 = __builtin_amdgcn_mfma_f32_16x16x32_f16(al, H0, aL0, 0, 0, 0);    \
        aH1 = __builtin_amdgcn_mfma_f32_16x16x32_f16(ah, H1, aH1, 0, 0, 0);    \
        aL1 = __builtin_amdgcn_mfma_f32_16x16x32_f16(ah, L1, aL1, 0, 0, 0);    \
        aL1 = __builtin_amdgcn_mfma_f32_16x16x32_f16(al, H1, aL1, 0, 0, 0);    \
    } while (0)

    // prologue: X0(0), W0(0), W1(1), X1(1)  -> oldest 6 = chunk-0 operands
    LOADX(xa0, xb0, 0);
    LOADW(h00, l00, h10, l10, 0);
    LOADW(h01, l01, h11, l11, 1);
    LOADX(xa1, xb1, 1);

#pragma unroll 1
    for (int c = 0; c < 30; c += 2) {
        WVM(6);                                   // chunk c operands landed
        COMPUTE(xa0, xb0, h00, l00, h10, l10);
        LOADW(h00, l00, h10, l10, c + 2);
        LOADX(xa0, xb0, c + 2);
        WVM(6);                                   // chunk c+1 operands landed
        COMPUTE(xa1, xb1, h01, l01, h11, l11);
        LOADW(h01, l01, h11, l11, c + 3);
        LOADX(xa1, xb1, c + 3);
    }
    WVM(6);
    COMPUTE(xa0, xb0, h00, l00, h10, l10);        // chunk 30
    WVM(0);
    COMPUTE(xa1, xb1, h01, l01, h11, l11);        // chunk 31
#undef LOADX
#undef LOADW
#undef COMPUTE

    // ---- combine kh-partials via LDS (m89-verified C layout) ----
    const float inv = 1.f / 4096.f;
#pragma unroll
    for (int e = 0; e < 4; ++e) {
        const int row = (lane >> 4) * 4 + e;      // token 0..15
        red[kh][row][nh * 32 + (lane & 15)]      = aH0[e] + aL0[e] * inv;
        red[kh][row][nh * 32 + 16 + (lane & 15)] = aH1[e] + aL1[e] * inv;
    }
    __syncthreads();

    // ---- epilogue: wave wv -> tokens [wv*4, wv*4+4); lane = expert ----
    float sumP_acc = 0.f;
    float cnt_acc  = 0.f;
#pragma unroll 1
    for (int tt = 0; tt < 4; ++tt) {
        const int tl = wv * 4 + tt;
        const size_t t = tok0 + tl;
        float v = red[0][tl][lane] + red[1][tl][lane];

        float m = v;
#pragma unroll
        for (int off = 32; off; off >>= 1) m = fmaxf(m, __shfl_xor(m, off, 64));
        float p = expf(v - m);
        float s = p;
#pragma unroll
        for (int off = 32; off; off >>= 1) s += __shfl_xor(s, off, 64);
        float prob = p / s;
        sumP_acc += prob;

        // top-1 (ties -> lowest index, matches lax.top_k)
        float bv = prob; int bi = lane;
#pragma unroll
        for (int off = 32; off; off >>= 1) {
            float ov = __shfl_xor(bv, off, 64);
            int   oi = __shfl_xor(bi, off, 64);
            if (ov > bv || (ov == bv && oi < bi)) { bv = ov; bi = oi; }
        }
        // top-2
        float v2 = (lane == bi) ? -1.f : prob;
        float bv2 = v2; int bi2 = lane;
#pragma unroll
        for (int off = 32; off; off >>= 1) {
            float ov = __shfl_xor(bv2, off, 64);
            int   oi = __shfl_xor(bi2, off, 64);
            if (ov > bv2 || (ov == bv2 && oi < bi2)) { bv2 = ov; bi2 = oi; }
        }

        float denom = bv + bv2;
        float g1 = bv / denom, g2 = bv2 / denom;
        float g = (lane == bi) ? g1 : ((lane == bi2) ? g2 : 0.f);
        gate_out[t * EE + lane] = g;
        if (lane == 0) {
            idx_out[2 * t]     = (float)bi;
            idx_out[2 * t + 1] = (float)bi2;
        }
        cnt_acc += (lane == bi)  ? 1.f : 0.f;
        cnt_acc += (lane == bi2) ? 1.f : 0.f;
    }

    // ---- per-block aux partials (deterministic) ----
    auxsm[0][wv][lane] = sumP_acc;
    auxsm[1][wv][lane] = cnt_acc;
    __syncthreads();
    if (wv == 0) {
        float sp = 0.f, c2 = 0.f;
#pragma unroll
        for (int w = 0; w < 4; ++w) {
            sp += auxsm[0][w][lane];
            c2 += auxsm[1][w][lane];
        }
        pSum[(size_t)blockIdx.x * 64 + lane] = sp;
        pCnt[(size_t)blockIdx.x * 64 + lane] = c2;
    }
}

// parallel aux reduction: 1024 threads (16 waves), 4-deep ILP + LDS reduce
__global__ __launch_bounds__(1024) void aux_kernel(
    const float* __restrict__ pSum, const float* __restrict__ pCnt,
    float* __restrict__ aux_out, int nblocks, float scale)
{
    const int tid  = threadIdx.x;
    const int wv   = tid >> 6;       // 0..15
    const int lane = tid & 63;       // = expert id
    __shared__ float smem[2][16][64];

    float sp[4] = {0.f, 0.f, 0.f, 0.f};
    float cc[4] = {0.f, 0.f, 0.f, 0.f};
    for (int b = wv * 4; b < nblocks; b += 64) {
#pragma unroll
        for (int u = 0; u < 4; ++u) {
            sp[u] += pSum[(size_t)(b + u) * 64 + lane];
            cc[u] += pCnt[(size_t)(b + u) * 64 + lane];
        }
    }
    smem[0][wv][lane] = (sp[0] + sp[1]) + (sp[2] + sp[3]);
    smem[1][wv][lane] = (cc[0] + cc[1]) + (cc[2] + cc[3]);
    __syncthreads();
    if (wv == 0) {
        float SP = 0.f, C = 0.f;
#pragma unroll
        for (int w = 0; w < 16; ++w) {
            SP += smem[0][w][lane];
            C  += smem[1][w][lane];
        }
        float prod = SP * C;
#pragma unroll
        for (int off = 32; off; off >>= 1) prod += __shfl_xor(prod, off, 64);
        if (lane == 0) aux_out[0] = prod * scale;
    }
}

extern "C" void kernel_launch(void* const* d_in, const int* in_sizes, int n_in,
                              void* d_out, int out_size, void* d_ws, size_t ws_size,
                              hipStream_t stream) {
    const float* x  = (const float*)d_in[0];
    const float* Wg = (const float*)d_in[1];
    const int T = in_sizes[0] / DD;          // 16384

    float* out      = (float*)d_out;
    float* gate_out = out;                                // T*64
    float* idx_out  = out + (size_t)T * EE;               // T*2 (as float)
    float* aux_out  = idx_out + (size_t)T * 2;            // 1

    const int nblocks = T / BM;                           // 1024
    _Float16* wF = (_Float16*)d_ws;                       // 512 KB frag-linear
    float* pSum = (float*)(wF + (size_t)64 * 4 * 2 * 512);// nblocks*64
    float* pCnt = pSum + (size_t)nblocks * 64;            // nblocks*64

    wsplit_kernel<<<64, 256, 0, stream>>>(Wg, wF);
    gate_kernel<<<nblocks, 256, 0, stream>>>(x, wF, gate_out, idx_out, pSum, pCnt);

    const float scale = (float)EE / ((float)T * (float)T);
    aux_kernel<<<1, 1024, 0, stream>>>(pSum, pCnt, aux_out, nblocks, scale);
}

// Round 16
// 56.554 us; speedup vs baseline: 1.2838x; 1.2306x over previous
//
#include <hip/hip_runtime.h>

// TopKGate via split-precision f16 MFMA (no fp32 MFMA on CDNA4):
//   x = xh + xl/4096, w = wh + wl/4096 (f16 planes, lo pre-scaled x4096)
//   logits = xh*wh + (xh*wl' + xl'*wh)/4096
// R16: x via DEEP global_load_lds staging (4 bufs, stage-ahead-3 -> ~48KB
// in-flight/CU, Little's law satisfied); w direct-to-fragment from the
// fragment-linear L2-resident wF (R15-proven). 1 DMA/thread + 4 reg loads
// per chunk, uniform vmcnt(5), 2 barriers/chunk. BM=16, grid 1024,
// waves = (kh: K-half) x (nh: expert-half), mfma_f32_16x16x32_f16.

typedef __attribute__((ext_vector_type(8))) _Float16 half8;
typedef __attribute__((ext_vector_type(4))) float f32x4;

constexpr int DD  = 2048;
constexpr int EE  = 64;
constexpr int BM  = 16;          // tokens per block
constexpr int BK  = 64;          // k per staged x chunk
constexpr int NCH = DD / BK;     // 32 chunks

#define WVM(N) asm volatile("s_waitcnt vmcnt(" #N ")" ::: "memory")
#define BAR()  asm volatile("s_barrier" ::: "memory")

// ---- pre-kernel (R15-proven): Wg[2048][64] -> fragment-linear wF ----
// wF[(((kc*4 + t)*2 + p)*64 + l)*8 + j] = plane_p( Wg[kc*32+(l>>4)*8+j][t*16+(l&15)] )
__global__ __launch_bounds__(256) void wsplit_kernel(
    const float* __restrict__ Wg, _Float16* __restrict__ wF)
{
    __shared__ float xl[32][65];
    const int tid = threadIdx.x;
    const int kc  = blockIdx.x;          // 64 blocks, 32 k's each
    const int k0  = kc * 32;
#pragma unroll
    for (int r = 0; r < 2; ++r) {
        int slot = tid + r * 256;        // float4 slots 0..511
        int row = slot >> 4, c4 = (slot & 15) << 2;
        *(float4*)&xl[row][c4] = *(const float4*)&Wg[(size_t)(k0 + row) * EE + c4];
    }
    __syncthreads();
    const int t = tid >> 6, l = tid & 63;
    const int e  = t * 16 + (l & 15);
    const int kl = (l >> 4) * 8;
    half8 hh, ll;
#pragma unroll
    for (int j = 0; j < 8; ++j) {
        float v = xl[kl + j][e];
        _Float16 h = (_Float16)v;
        hh[j] = h;
        ll[j] = (_Float16)((v - (float)h) * 4096.f);
    }
    const size_t base = ((size_t)(kc * 4 + t) * 2) * 512 + (size_t)l * 8;
    *(half8*)&wF[base]       = hh;       // hi plane
    *(half8*)&wF[base + 512] = ll;       // lo plane
}

__global__ __launch_bounds__(256, 4) void gate_kernel(
    const float* __restrict__ x, const _Float16* __restrict__ wF,
    float* __restrict__ gate_out, float* __restrict__ idx_out,
    float* __restrict__ pSum, float* __restrict__ pCnt)
{
    __shared__ __align__(16) float xs[4][BM][BK];   // 16 KB, 4-deep x staging
    __shared__ float red[2][BM][68];                // kh-partials (~8.7 KB)
    __shared__ float auxsm[2][4][64];               // 2 KB

    const int tid  = threadIdx.x;
    const int wv   = tid >> 6;
    const int lane = tid & 63;
    const int kh   = wv & 1;             // K-half (32 k's of each 64-k chunk)
    const int nh   = wv >> 1;            // expert-half (tiles 2nh, 2nh+1)
    const size_t tok0 = (size_t)blockIdx.x * BM;
    const float* xg = x + tok0 * DD;

    // ---- x staging: 1 dwordx4 DMA per thread per chunk, 32B source-XOR ----
    const int srow = tid >> 4;           // 0..15
    const int scb  = (tid & 15) << 4;    // dest byte col
    const int ssb  = scb ^ ((srow & 7) << 5);
    auto stageX = [&](int buf, int c) {
        __builtin_amdgcn_global_load_lds(
            xg + (size_t)srow * DD + c * BK + (ssb >> 2),
            &xs[buf][srow][scb >> 2], 16, 0, 0);
    };

    // ---- w fragment pointers (32-k chunk index = 2c + kh) ----
    const size_t tile0 = (((size_t)kh * 4 + nh * 2) * 2) * 512 + (size_t)lane * 8;
    const _Float16* w00 = wF + tile0;           // tile 2nh,   hi
    const _Float16* w01 = wF + tile0 + 512;     // tile 2nh,   lo
    const _Float16* w10 = wF + tile0 + 1024;    // tile 2nh+1, hi
    const _Float16* w11 = wF + tile0 + 1536;    // tile 2nh+1, lo
    half8 wA0, wA1, wA2, wA3, wB0, wB1, wB2, wB3;

#define LOADW(R0, R1, R2, R3, c)                                               \
    do { const size_t o = (size_t)(c) * 8192;                                  \
         R0 = *(const half8*)(w00 + o); R1 = *(const half8*)(w01 + o);         \
         R2 = *(const half8*)(w10 + o); R3 = *(const half8*)(w11 + o); } while (0)

    f32x4 aH0 = {0.f,0.f,0.f,0.f}, aL0 = {0.f,0.f,0.f,0.f};
    f32x4 aH1 = {0.f,0.f,0.f,0.f}, aL1 = {0.f,0.f,0.f,0.f};

    const int rrow = lane & 15;
    const int rfb  = (kh * 128 + (lane >> 4) * 32) ^ ((rrow & 7) << 5); // byte

#define COMPUTE(buf, W0, W1, W2, W3)                                           \
    do {                                                                       \
        const float* p = (const float*)((const char*)&xs[buf][rrow][0] + rfb); \
        float4 xa = *(const float4*)p;                                         \
        float4 xb = *(const float4*)(p + 4);                                   \
        half8 ah, al; float v;                                                 \
        v = xa.x; { _Float16 h=(_Float16)v; ah[0]=h; al[0]=(_Float16)((v-(float)h)*4096.f); } \
        v = xa.y; { _Float16 h=(_Float16)v; ah[1]=h; al[1]=(_Float16)((v-(float)h)*4096.f); } \
        v = xa.z; { _Float16 h=(_Float16)v; ah[2]=h; al[2]=(_Float16)((v-(float)h)*4096.f); } \
        v = xa.w; { _Float16 h=(_Float16)v; ah[3]=h; al[3]=(_Float16)((v-(float)h)*4096.f); } \
        v = xb.x; { _Float16 h=(_Float16)v; ah[4]=h; al[4]=(_Float16)((v-(float)h)*4096.f); } \
        v = xb.y; { _Float16 h=(_Float16)v; ah[5]=h; al[5]=(_Float16)((v-(float)h)*4096.f); } \
        v = xb.z; { _Float16 h=(_Float16)v; ah[6]=h; al[6]=(_Float16)((v-(float)h)*4096.f); } \
        v = xb.w; { _Float16 h=(_Float16)v; ah[7]=h; al[7]=(_Float16)((v-(float)h)*4096.f); } \
        aH0 = __builtin_amdgcn_mfma_f32_16x16x32_f16(ah, W0, aH0, 0, 0, 0);    \
        aL0 = __builtin_amdgcn_mfma_f32_16x16x32_f16(ah, W1, aL0, 0, 0, 0);    \
        aL0 = __builtin_amdgcn_mfma_f32_16x16x32_f16(al, W0, aL0, 0, 0, 0);    \
        aH1 = __builtin_amdgcn_mfma_f32_16x16x32_f16(ah, W2, aH1, 0, 0, 0);    \
        aL1 = __builtin_amdgcn_mfma_f32_16x16x32_f16(ah, W3, aL1, 0, 0, 0);    \
        aL1 = __builtin_amdgcn_mfma_f32_16x16x32_f16(al, W2, aL1, 0, 0, 0);    \
    } while (0)

    // prologue (issue order fixed by the asm fences): x0 x1 W0 x2 W1
    stageX(0, 0);
    stageX(1, 1);
    LOADW(wA0, wA1, wA2, wA3, 0);
    stageX(2, 2);
    LOADW(wB0, wB1, wB2, wB3, 1);

#pragma unroll 1
    for (int c = 0; c < NCH; ++c) {
        if (c < NCH - 1) { WVM(5); } else { WVM(0); }
        BAR();                                    // chunk c staged for all waves
        if (c & 1) {
            COMPUTE(c & 3, wB0, wB1, wB2, wB3);
            if (c + 2 < NCH) LOADW(wB0, wB1, wB2, wB3, c + 2);
        } else {
            COMPUTE(c & 3, wA0, wA1, wA2, wA3);
            if (c + 2 < NCH) LOADW(wA0, wA1, wA2, wA3, c + 2);
        }
        if (c + 3 < NCH) stageX((c + 3) & 3, c + 3);
        BAR();                                    // all waves done reading buf c
    }
#undef LOADW
#undef COMPUTE

    // ---- combine kh-partials via LDS (m89-verified C layout) ----
    const float inv = 1.f / 4096.f;
#pragma unroll
    for (int e = 0; e < 4; ++e) {
        const int row = (lane >> 4) * 4 + e;      // token 0..15
        red[kh][row][nh * 32 + (lane & 15)]      = aH0[e] + aL0[e] * inv;
        red[kh][row][nh * 32 + 16 + (lane & 15)] = aH1[e] + aL1[e] * inv;
    }
    __syncthreads();

    // ---- epilogue: wave wv -> tokens [wv*4, wv*4+4); lane = expert ----
    float sumP_acc = 0.f;
    float cnt_acc  = 0.f;
#pragma unroll 1
    for (int tt = 0; tt < 4; ++tt) {
        const int tl = wv * 4 + tt;
        const size_t t = tok0 + tl;
        float v = red[0][tl][lane] + red[1][tl][lane];

        float m = v;
#pragma unroll
        for (int off = 32; off; off >>= 1) m = fmaxf(m, __shfl_xor(m, off, 64));
        float p = expf(v - m);
        float s = p;
#pragma unroll
        for (int off = 32; off; off >>= 1) s += __shfl_xor(s, off, 64);
        float prob = p / s;
        sumP_acc += prob;

        // top-1 (ties -> lowest index, matches lax.top_k)
        float bv = prob; int bi = lane;
#pragma unroll
        for (int off = 32; off; off >>= 1) {
            float ov = __shfl_xor(bv, off, 64);
            int   oi = __shfl_xor(bi, off, 64);
            if (ov > bv || (ov == bv && oi < bi)) { bv = ov; bi = oi; }
        }
        // top-2
        float v2 = (lane == bi) ? -1.f : prob;
        float bv2 = v2; int bi2 = lane;
#pragma unroll
        for (int off = 32; off; off >>= 1) {
            float ov = __shfl_xor(bv2, off, 64);
            int   oi = __shfl_xor(bi2, off, 64);
            if (ov > bv2 || (ov == bv2 && oi < bi2)) { bv2 = ov; bi2 = oi; }
        }

        float denom = bv + bv2;
        float g1 = bv / denom, g2 = bv2 / denom;
        float g = (lane == bi) ? g1 : ((lane == bi2) ? g2 : 0.f);
        gate_out[t * EE + lane] = g;
        if (lane == 0) {
            idx_out[2 * t]     = (float)bi;
            idx_out[2 * t + 1] = (float)bi2;
        }
        cnt_acc += (lane == bi)  ? 1.f : 0.f;
        cnt_acc += (lane == bi2) ? 1.f : 0.f;
    }

    // ---- per-block aux partials (deterministic) ----
    auxsm[0][wv][lane] = sumP_acc;
    auxsm[1][wv][lane] = cnt_acc;
    __syncthreads();
    if (wv == 0) {
        float sp = 0.f, c2 = 0.f;
#pragma unroll
        for (int w = 0; w < 4; ++w) {
            sp += auxsm[0][w][lane];
            c2 += auxsm[1][w][lane];
        }
        pSum[(size_t)blockIdx.x * 64 + lane] = sp;
        pCnt[(size_t)blockIdx.x * 64 + lane] = c2;
    }
}

// parallel aux reduction: 1024 threads (16 waves), 4-deep ILP + LDS reduce
__global__ __launch_bounds__(1024) void aux_kernel(
    const float* __restrict__ pSum, const float* __restrict__ pCnt,
    float* __restrict__ aux_out, int nblocks, float scale)
{
    const int tid  = threadIdx.x;
    const int wv   = tid >> 6;       // 0..15
    const int lane = tid & 63;       // = expert id
    __shared__ float smem[2][16][64];

    float sp[4] = {0.f, 0.f, 0.f, 0.f};
    float cc[4] = {0.f, 0.f, 0.f, 0.f};
    for (int b = wv * 4; b < nblocks; b += 64) {
#pragma unroll
        for (int u = 0; u < 4; ++u) {
            sp[u] += pSum[(size_t)(b + u) * 64 + lane];
            cc[u] += pCnt[(size_t)(b + u) * 64 + lane];
        }
    }
    smem[0][wv][lane] = (sp[0] + sp[1]) + (sp[2] + sp[3]);
    smem[1][wv][lane] = (cc[0] + cc[1]) + (cc[2] + cc[3]);
    __syncthreads();
    if (wv == 0) {
        float SP = 0.f, C = 0.f;
#pragma unroll
        for (int w = 0; w < 16; ++w) {
            SP += smem[0][w][lane];
            C  += smem[1][w][lane];
        }
        float prod = SP * C;
#pragma unroll
        for (int off = 32; off; off >>= 1) prod += __shfl_xor(prod, off, 64);
        if (lane == 0) aux_out[0] = prod * scale;
    }
}

extern "C" void kernel_launch(void* const* d_in, const int* in_sizes, int n_in,
                              void* d_out, int out_size, void* d_ws, size_t ws_size,
                              hipStream_t stream) {
    const float* x  = (const float*)d_in[0];
    const float* Wg = (const float*)d_in[1];
    const int T = in_sizes[0] / DD;          // 16384

    float* out      = (float*)d_out;
    float* gate_out = out;                                // T*64
    float* idx_out  = out + (size_t)T * EE;               // T*2 (as float)
    float* aux_out  = idx_out + (size_t)T * 2;            // 1

    const int nblocks = T / BM;                           // 1024
    _Float16* wF = (_Float16*)d_ws;                       // 512 KB frag-linear
    float* pSum = (float*)(wF + (size_t)64 * 4 * 2 * 512);// nblocks*64
    float* pCnt = pSum + (size_t)nblocks * 64;            // nblocks*64

    wsplit_kernel<<<64, 256, 0, stream>>>(Wg, wF);
    gate_kernel<<<nblocks, 256, 0, stream>>>(x, wF, gate_out, idx_out, pSum, pCnt);

    const float scale = (float)EE / ((float)T * (float)T);
    aux_kernel<<<1, 1024, 0, stream>>>(pSum, pCnt, aux_out, nblocks, scale);
}

// Round 17
// 53.892 us; speedup vs baseline: 1.3472x; 1.0494x over previous
//
#include <hip/hip_runtime.h>

// TopKGate via split-precision f16 MFMA (no fp32 MFMA on CDNA4):
//   x = xh + xl/4096, w = wh + wl/4096 (f16 planes, lo pre-scaled x4096)
//   logits = xh*wh + (xh*wl' + xl'*wh)/4096
// R17: waves = 4 K-QUARTERS (kq). Each wave computes all 4 expert tiles from
// ONE x->f16 conversion (CVT per x element exactly once per block; was 2x).
// 128-k chunks (16 total, half the barriers). x staged via global_load_lds
// (NBUF=3, stage-after-barrier, counted WVM(2)); w direct-to-fragment from
// fragment-linear wF (R15-proven). BM=16, grid 1024, mfma_f32_16x16x32_f16.

typedef __attribute__((ext_vector_type(8))) _Float16 half8;
typedef __attribute__((ext_vector_type(4))) float f32x4;

constexpr int DD  = 2048;
constexpr int EE  = 64;
constexpr int BM  = 16;          // tokens per block
constexpr int BK  = 128;         // k per staged chunk (each wave: 32-k quarter)
constexpr int NCH = DD / BK;     // 16 chunks

#define WVM(N) asm volatile("s_waitcnt vmcnt(" #N ")" ::: "memory")
#define BAR()  asm volatile("s_barrier" ::: "memory")

// ---- pre-kernel (R15-proven): Wg[2048][64] -> fragment-linear wF ----
// wF[(kc*8 + t*2 + p)*512 + l*8 + j] = plane_p( Wg[kc*32+(l>>4)*8+j][t*16+(l&15)] )
__global__ __launch_bounds__(256) void wsplit_kernel(
    const float* __restrict__ Wg, _Float16* __restrict__ wF)
{
    __shared__ float xl[32][65];
    const int tid = threadIdx.x;
    const int kc  = blockIdx.x;          // 64 blocks, 32 k's each
    const int k0  = kc * 32;
#pragma unroll
    for (int r = 0; r < 2; ++r) {
        int slot = tid + r * 256;        // float4 slots 0..511
        int row = slot >> 4, c4 = (slot & 15) << 2;
        *(float4*)&xl[row][c4] = *(const float4*)&Wg[(size_t)(k0 + row) * EE + c4];
    }
    __syncthreads();
    const int t = tid >> 6, l = tid & 63;
    const int e  = t * 16 + (l & 15);
    const int kl = (l >> 4) * 8;
    half8 hh, ll;
#pragma unroll
    for (int j = 0; j < 8; ++j) {
        float v = xl[kl + j][e];
        _Float16 h = (_Float16)v;
        hh[j] = h;
        ll[j] = (_Float16)((v - (float)h) * 4096.f);
    }
    const size_t base = (size_t)(kc * 8 + t * 2) * 512 + (size_t)l * 8;
    *(half8*)&wF[base]       = hh;       // hi plane
    *(half8*)&wF[base + 512] = ll;       // lo plane
}

__global__ __launch_bounds__(256, 4) void gate_kernel(
    const float* __restrict__ x, const _Float16* __restrict__ wF,
    float* __restrict__ gate_out, float* __restrict__ idx_out,
    float* __restrict__ pSum, float* __restrict__ pCnt)
{
    __shared__ __align__(16) union {
        float xs[3][BM][BK];                               // 24 KB staging
        struct { float red[4][BM][68]; float auxsm[2][4][64]; } ep; // 19.5 KB
    } sm;

    const int tid  = threadIdx.x;
    const int kq   = tid >> 6;           // wave = K-quarter of chunk (32 k's)
    const int lane = tid & 63;
    const size_t tok0 = (size_t)blockIdx.x * BM;
    const float* xg = x + tok0 * DD;

    // ---- x staging: 2 dwordx4 DMA per thread per chunk, 32B source-XOR ----
    auto stageX = [&](int buf, int c) {
#pragma unroll
        for (int r = 0; r < 2; ++r) {
            int slot = tid + r * 256;            // float4 slot 0..511
            int row  = slot >> 5;                // 0..15
            int cb   = (slot & 31) << 4;         // dest byte 0..511
            int sb   = cb ^ ((row & 7) << 5);    // source-swizzled byte
            __builtin_amdgcn_global_load_lds(
                xg + (size_t)row * DD + c * BK + (sb >> 2),
                &sm.xs[buf][row][cb >> 2], 16, 0, 0);
        }
    };

    f32x4 aH[4], aL[4];
#pragma unroll
    for (int t = 0; t < 4; ++t) {
        aH[t] = (f32x4){0.f, 0.f, 0.f, 0.f};
        aL[t] = (f32x4){0.f, 0.f, 0.f, 0.f};
    }

    const int rrow = lane & 15;          // token row
    const int rb   = (kq * 128 + ((lane >> 4) * 32)) ^ ((rrow & 7) << 5);

    auto compute = [&](int buf, int c) {
        // w fragments for this wave's 32-k slice (kc = c*4 + kq), all 4 tiles
        const _Float16* wb = wF + (size_t)(c * 4 + kq) * 4096 + (size_t)lane * 8;
        half8 wh[4], wl[4];
#pragma unroll
        for (int t = 0; t < 4; ++t) {
            wh[t] = *(const half8*)(wb + (t * 2) * 512);
            wl[t] = *(const half8*)(wb + (t * 2 + 1) * 512);
        }
        // x fragment: one 8-float read, split once
        const float* p = (const float*)((const char*)&sm.xs[buf][rrow][0] + rb);
        float4 xa = *(const float4*)p;
        float4 xb = *(const float4*)(p + 4);
        half8 ah, al;
        {
            float v;
            v = xa.x; { _Float16 h=(_Float16)v; ah[0]=h; al[0]=(_Float16)((v-(float)h)*4096.f); }
            v = xa.y; { _Float16 h=(_Float16)v; ah[1]=h; al[1]=(_Float16)((v-(float)h)*4096.f); }
            v = xa.z; { _Float16 h=(_Float16)v; ah[2]=h; al[2]=(_Float16)((v-(float)h)*4096.f); }
            v = xa.w; { _Float16 h=(_Float16)v; ah[3]=h; al[3]=(_Float16)((v-(float)h)*4096.f); }
            v = xb.x; { _Float16 h=(_Float16)v; ah[4]=h; al[4]=(_Float16)((v-(float)h)*4096.f); }
            v = xb.y; { _Float16 h=(_Float16)v; ah[5]=h; al[5]=(_Float16)((v-(float)h)*4096.f); }
            v = xb.z; { _Float16 h=(_Float16)v; ah[6]=h; al[6]=(_Float16)((v-(float)h)*4096.f); }
            v = xb.w; { _Float16 h=(_Float16)v; ah[7]=h; al[7]=(_Float16)((v-(float)h)*4096.f); }
        }
#pragma unroll
        for (int t = 0; t < 4; ++t) {
            aH[t] = __builtin_amdgcn_mfma_f32_16x16x32_f16(ah, wh[t], aH[t], 0, 0, 0);
            aL[t] = __builtin_amdgcn_mfma_f32_16x16x32_f16(ah, wl[t], aL[t], 0, 0, 0);
            aL[t] = __builtin_amdgcn_mfma_f32_16x16x32_f16(al, wh[t], aL[t], 0, 0, 0);
        }
    };

    // prologue: 2 stages in flight
    stageX(0, 0);
    stageX(1, 1);

#pragma unroll 1
    for (int c = 0; c < NCH; ++c) {
        if (c < NCH - 1) { WVM(2); } else { WVM(0); }  // stage(c) landed
        BAR();                                   // visible to all waves
        compute(c % 3, c);
        BAR();                                   // all waves done reading buf
        if (c + 2 < NCH) stageX((c + 2) % 3, c + 2);
    }

    // ---- K-partials -> LDS (m89-verified C layout), combine planes ----
    __syncthreads();
    const float inv = 1.f / 4096.f;
#pragma unroll
    for (int e = 0; e < 4; ++e) {
        const int row = (lane >> 4) * 4 + e;     // token 0..15
#pragma unroll
        for (int t = 0; t < 4; ++t)
            sm.ep.red[kq][row][t * 16 + (lane & 15)] = aH[t][e] + aL[t][e] * inv;
    }
    __syncthreads();

    // ---- epilogue: wave kq -> tokens [kq*4, kq*4+4); lane = expert ----
    float sumP_acc = 0.f;
    float cnt_acc  = 0.f;
#pragma unroll 1
    for (int tt = 0; tt < 4; ++tt) {
        const int tl = kq * 4 + tt;
        const size_t t = tok0 + tl;
        float v = (sm.ep.red[0][tl][lane] + sm.ep.red[1][tl][lane])
                + (sm.ep.red[2][tl][lane] + sm.ep.red[3][tl][lane]);

        float m = v;
#pragma unroll
        for (int off = 32; off; off >>= 1) m = fmaxf(m, __shfl_xor(m, off, 64));
        float p = expf(v - m);
        float s = p;
#pragma unroll
        for (int off = 32; off; off >>= 1) s += __shfl_xor(s, off, 64);
        float prob = p / s;
        sumP_acc += prob;

        // top-1 (ties -> lowest index, matches lax.top_k)
        float bv = prob; int bi = lane;
#pragma unroll
        for (int off = 32; off; off >>= 1) {
            float ov = __shfl_xor(bv, off, 64);
            int   oi = __shfl_xor(bi, off, 64);
            if (ov > bv || (ov == bv && oi < bi)) { bv = ov; bi = oi; }
        }
        // top-2
        float v2 = (lane == bi) ? -1.f : prob;
        float bv2 = v2; int bi2 = lane;
#pragma unroll
        for (int off = 32; off; off >>= 1) {
            float ov = __shfl_xor(bv2, off, 64);
            int   oi = __shfl_xor(bi2, off, 64);
            if (ov > bv2 || (ov == bv2 && oi < bi2)) { bv2 = ov; bi2 = oi; }
        }

        float denom = bv + bv2;
        float g1 = bv / denom, g2 = bv2 / denom;
        float g = (lane == bi) ? g1 : ((lane == bi2) ? g2 : 0.f);
        gate_out[t * EE + lane] = g;
        if (lane == 0) {
            idx_out[2 * t]     = (float)bi;
            idx_out[2 * t + 1] = (float)bi2;
        }
        cnt_acc += (lane == bi)  ? 1.f : 0.f;
        cnt_acc += (lane == bi2) ? 1.f : 0.f;
    }

    // ---- per-block aux partials (deterministic) ----
    sm.ep.auxsm[0][kq][lane] = sumP_acc;
    sm.ep.auxsm[1][kq][lane] = cnt_acc;
    __syncthreads();
    if (kq == 0) {
        float sp = 0.f, c2 = 0.f;
#pragma unroll
        for (int w = 0; w < 4; ++w) {
            sp += sm.ep.auxsm[0][w][lane];
            c2 += sm.ep.auxsm[1][w][lane];
        }
        pSum[(size_t)blockIdx.x * 64 + lane] = sp;
        pCnt[(size_t)blockIdx.x * 64 + lane] = c2;
    }
}

// parallel aux reduction: 1024 threads (16 waves), 4-deep ILP + LDS reduce
__global__ __launch_bounds__(1024) void aux_kernel(
    const float* __restrict__ pSum, const float* __restrict__ pCnt,
    float* __restrict__ aux_out, int nblocks, float scale)
{
    const int tid  = threadIdx.x;
    const int wv   = tid >> 6;       // 0..15
    const int lane = tid & 63;       // = expert id
    __shared__ float smem[2][16][64];

    float sp[4] = {0.f, 0.f, 0.f, 0.f};
    float cc[4] = {0.f, 0.f, 0.f, 0.f};
    for (int b = wv * 4; b < nblocks; b += 64) {
#pragma unroll
        for (int u = 0; u < 4; ++u) {
            sp[u] += pSum[(size_t)(b + u) * 64 + lane];
            cc[u] += pCnt[(size_t)(b + u) * 64 + lane];
        }
    }
    smem[0][wv][lane] = (sp[0] + sp[1]) + (sp[2] + sp[3]);
    smem[1][wv][lane] = (cc[0] + cc[1]) + (cc[2] + cc[3]);
    __syncthreads();
    if (wv == 0) {
        float SP = 0.f, C = 0.f;
#pragma unroll
        for (int w = 0; w < 16; ++w) {
            SP += smem[0][w][lane];
            C  += smem[1][w][lane];
        }
        float prod = SP * C;
#pragma unroll
        for (int off = 32; off; off >>= 1) prod += __shfl_xor(prod, off, 64);
        if (lane == 0) aux_out[0] = prod * scale;
    }
}

extern "C" void kernel_launch(void* const* d_in, const int* in_sizes, int n_in,
                              void* d_out, int out_size, void* d_ws, size_t ws_size,
                              hipStream_t stream) {
    const float* x  = (const float*)d_in[0];
    const float* Wg = (const float*)d_in[1];
    const int T = in_sizes[0] / DD;          // 16384

    float* out      = (float*)d_out;
    float* gate_out = out;                                // T*64
    float* idx_out  = out + (size_t)T * EE;               // T*2 (as float)
    float* aux_out  = idx_out + (size_t)T * 2;            // 1

    const int nblocks = T / BM;                           // 1024
    _Float16* wF = (_Float16*)d_ws;                       // 512 KB frag-linear
    float* pSum = (float*)(wF + (size_t)64 * 8 * 512);    // nblocks*64
    float* pCnt = pSum + (size_t)nblocks * 64;            // nblocks*64

    wsplit_kernel<<<64, 256, 0, stream>>>(Wg, wF);
    gate_kernel<<<nblocks, 256, 0, stream>>>(x, wF, gate_out, idx_out, pSum, pCnt);

    const float scale = (float)EE / ((float)T * (float)T);
    aux_kernel<<<1, 1024, 0, stream>>>(pSum, pCnt, aux_out, nblocks, scale);
}